// Round 4
// baseline (160.007 us; speedup 1.0000x reference)
//
#include <hip/hip_runtime.h>

#define BATCH 8192
#define INC   512
#define OUTC  512
#define NB    8
#define KDIM  (INC * NB)     // 4096
#define SPLITK 4
#define KQ    (KDIM / SPLITK) // 1024 k per block (128 i's)
#define BK    64
#define NKT   (KQ / BK)       // 16
#define BM    128
#define BN    128
#define THREADS 128

typedef __attribute__((ext_vector_type(8))) short bf16x8;
typedef __attribute__((ext_vector_type(4))) float f32x4;
typedef __attribute__((ext_vector_type(4))) int   i32x4;

// truncate-pack two fp32 into two bf16 (lo -> low 16 bits) in one v_perm_b32
static __device__ __forceinline__ unsigned int pk2(float lo, float hi) {
    return __builtin_amdgcn_perm(__builtin_bit_cast(unsigned int, hi),
                                 __builtin_bit_cast(unsigned int, lo),
                                 0x07060302u);
}

// ---- prepass 1: W fp32 -> bf16 (RNE) ----
__global__ __launch_bounds__(256)
void w_prepass(const float* __restrict__ W, unsigned short* __restrict__ Wb) {
    const int base = (blockIdx.x * 256 + threadIdx.x) * 8;
    const float4 a = *(const float4*)(W + base);
    const float4 b = *(const float4*)(W + base + 4);
    const float v[8] = {a.x, a.y, a.z, a.w, b.x, b.y, b.z, b.w};
    unsigned int r[8];
#pragma unroll
    for (int i = 0; i < 8; ++i) {
        unsigned int t = __builtin_bit_cast(unsigned int, v[i]);
        t += 0x7FFFu + ((t >> 16) & 1u);
        r[i] = t >> 16;
    }
    *(i32x4*)(Wb + base) = (i32x4){(int)(r[0] | (r[1] << 16)), (int)(r[2] | (r[3] << 16)),
                                   (int)(r[4] | (r[5] << 16)), (int)(r[6] | (r[7] << 16))};
}

// ---- prepass 2: X (BATCH,INC) -> XT (INC,BATCH) fp32 ----
__global__ __launch_bounds__(256)
void xt_prepass(const float* __restrict__ X, float* __restrict__ XT) {
    __shared__ float t[64][65];
    const int bx = blockIdx.x * 64;   // batch base
    const int iy = blockIdx.y * 64;   // in-feature base
    const int lx = threadIdx.x & 63;
    const int ly = threadIdx.x >> 6;  // 0..3
#pragma unroll
    for (int r = 0; r < 16; ++r) {
        const int row = ly * 16 + r;
        t[row][lx] = X[(size_t)(bx + row) * INC + iy + lx];
    }
    __syncthreads();
#pragma unroll
    for (int r = 0; r < 16; ++r) {
        const int row = ly * 16 + r;
        XT[(size_t)(iy + row) * BATCH + bx + lx] = t[lx][row];
    }
}

// B LDS layout (XOR-swizzled): element (row 0..127, kblk 0..7) at short offset
//   row*64 + (kblk ^ (row&7))*8
template <bool DMA, bool XTP>
__global__ __launch_bounds__(THREADS, 2)
void fused_gemm(const float* __restrict__ X,    // (BATCH, INC)
                const void*  __restrict__ Wsrc, // bf16 ws or fp32 W
                const float* __restrict__ XT,   // (INC, BATCH) or null
                const float* __restrict__ CEN,
                const float* __restrict__ SLP,
                float* __restrict__ Y)          // (BATCH, OUTC), pre-zeroed
{
    __shared__ short Bs[2][BN * BK];  // 2 x 16 KB

    const int tid  = threadIdx.x;
    const int lane = tid & 63;
    const int wave = tid >> 6;        // 0..1 : m-half of the block
    const int l15  = lane & 15;
    const int h    = lane >> 4;       // 0..3
    const int low3 = l15 & 7;

    const int b0 = blockIdx.x * BM;
    const int j0 = blockIdx.y * BN;
    const int kz = blockIdx.z;
    const int i00 = kz * (KQ / NB);   // this block's first input-feature (128 per kz)

    // sigmoid: s_m(x) = 1/(1 + exp2(pc*x + q0) * R^m)
    const float L2E = 1.4426950408889634f;
    const float g2  = 2.0f * SLP[0] * L2E;
    const float pc  = -g2;
    const float q0  = g2 * CEN[0];
    const float R   = __builtin_amdgcn_exp2f(g2 * (CEN[1] - CEN[0]));

    // B fragment read bases (per ks)
    const short* const brp0 = &Bs[0][l15 * 64 + ((0 + h) ^ low3) * 8];
    const short* const brp1 = &Bs[0][l15 * 64 + ((4 + h) ^ low3) * 8];

    // DMA lane mapping (global-side swizzle)
    const int dma_r  = lane >> 3;
    const int dma_kb = (lane & 7) ^ dma_r;

    const int mrow = b0 + wave * 64 + l15;   // + mf*16 later

    f32x4 acc[4][8];
#pragma unroll
    for (int i = 0; i < 4; ++i)
#pragma unroll
        for (int j = 0; j < 8; ++j)
            acc[i][j] = (f32x4){0.f, 0.f, 0.f, 0.f};

    float xv[8], xn[8];   // [ks*4 + mf]

#define LOADX(kt, dst)                                                         \
    {                                                                          \
        _Pragma("unroll")                                                      \
        for (int ks = 0; ks < 2; ++ks) {                                       \
            const int ii = i00 + (kt) * 8 + ks * 4 + h;                        \
            _Pragma("unroll")                                                  \
            for (int mf = 0; mf < 4; ++mf) {                                   \
                const int bb = mrow + mf * 16;                                 \
                (dst)[ks * 4 + mf] = XTP ? XT[(size_t)ii * BATCH + bb]         \
                                         : X[(size_t)bb * INC + ii];           \
            }                                                                  \
        }                                                                      \
    }

#define STAGEB(kt, buf)                                                        \
    {                                                                          \
        const int kg = kz * KQ + (kt) * BK;                                    \
        if constexpr (DMA) {                                                   \
            const unsigned short* Wb = (const unsigned short*)Wsrc;            \
            _Pragma("unroll")                                                  \
            for (int q = 0; q < 8; ++q) {                                      \
                const int cc = wave * 8 + q;                                   \
                const unsigned short* gp = Wb                                  \
                    + (size_t)(j0 + cc * 8 + dma_r) * KDIM + kg + dma_kb * 8;  \
                __builtin_amdgcn_global_load_lds(                              \
                    (const __attribute__((address_space(1))) void*)gp,         \
                    (__attribute__((address_space(3))) void*)(&Bs[buf][cc * 512]), \
                    16, 0, 0);                                                 \
            }                                                                  \
        } else {                                                               \
            const float* Wf = (const float*)Wsrc;                              \
            const int row = tid;                                               \
            const float* wp = Wf + (size_t)(j0 + row) * KDIM + kg;             \
            _Pragma("unroll")                                                  \
            for (int kb = 0; kb < 8; ++kb) {                                   \
                const float4 c0 = ((const float4*)wp)[2 * kb];                 \
                const float4 c1 = ((const float4*)wp)[2 * kb + 1];             \
                *(i32x4*)(&Bs[buf][row * 64 + ((kb ^ (row & 7)) * 8)]) =       \
                    (i32x4){(int)pk2(c0.x, c0.y), (int)pk2(c0.z, c0.w),        \
                            (int)pk2(c1.x, c1.y), (int)pk2(c1.z, c1.w)};       \
            }                                                                  \
        }                                                                      \
    }

    // prologue
    LOADX(0, xv);
    STAGEB(0, 0);

    for (int kt = 0; kt < NKT; ++kt) {
        const int cur = kt & 1;

        __syncthreads();   // buf[cur] staged (vmcnt/lgkm drained by compiler)

        if (kt + 1 < NKT) STAGEB(kt + 1, 1 - cur);
        const int ktn = (kt + 1 < NKT) ? (kt + 1) : (NKT - 1);
        LOADX(ktn, xn);

#pragma unroll
        for (int ks = 0; ks < 2; ++ks) {
            // issue B fragment reads first (latency covered by sigmoid chains)
            const short* brp = (ks ? brp1 : brp0) + cur * (BN * BK);
            bf16x8 bfr[8];
#pragma unroll
            for (int nf = 0; nf < 8; ++nf)
                bfr[nf] = *(const bf16x8*)(brp + nf * 1024);

            // A fragments in registers: lane's 8 elems = 8 basis of one (b,i)
            bf16x8 af[4];
#pragma unroll
            for (int mf = 0; mf < 4; ++mf) {
                float e = __builtin_amdgcn_exp2f(fmaf(pc, xv[ks * 4 + mf], q0));
                float s[NB];
#pragma unroll
                for (int m = 0; m < NB; ++m) {
                    s[m] = __builtin_amdgcn_rcpf(1.0f + e);
                    e *= R;
                }
                af[mf] = __builtin_bit_cast(bf16x8,
                    (i32x4){(int)pk2(s[0], s[1]), (int)pk2(s[2], s[3]),
                            (int)pk2(s[4], s[5]), (int)pk2(s[6], s[7])});
            }

#pragma unroll
            for (int mf = 0; mf < 4; ++mf)
#pragma unroll
                for (int nf = 0; nf < 8; ++nf)
                    acc[mf][nf] = __builtin_amdgcn_mfma_f32_16x16x32_bf16(
                        af[mf], bfr[nf], acc[mf][nf], 0, 0, 0);
        }

#pragma unroll
        for (int q = 0; q < 8; ++q) xv[q] = xn[q];
    }

    // epilogue: C/D layout col=lane&15, row=(lane>>4)*4+reg ; accumulate across kz
    const int rowb = b0 + wave * 64 + h * 4;
    const int colb = j0 + l15;
#pragma unroll
    for (int mf = 0; mf < 4; ++mf)
#pragma unroll
        for (int nf = 0; nf < 8; ++nf)
#pragma unroll
            for (int r = 0; r < 4; ++r)
                atomicAdd(&Y[(size_t)(rowb + mf * 16 + r) * OUTC + (colb + nf * 16)],
                          acc[mf][nf][r]);
#undef LOADX
#undef STAGEB
}

extern "C" void kernel_launch(void* const* d_in, const int* in_sizes, int n_in,
                              void* d_out, int out_size, void* d_ws, size_t ws_size,
                              hipStream_t stream) {
    const float* X   = (const float*)d_in[0];
    const float* W   = (const float*)d_in[1];
    const float* CEN = (const float*)d_in[2];
    const float* SLP = (const float*)d_in[3];
    float* Y = (float*)d_out;

    hipMemsetAsync(d_out, 0, (size_t)out_size * sizeof(float), stream);

    dim3 grid(BATCH / BM, OUTC / BN, SPLITK);   // 64 x 4 x 4 = 1024 blocks

    const size_t WB_BYTES = (size_t)OUTC * KDIM * sizeof(unsigned short); // 4 MB
    const size_t XT_BYTES = (size_t)BATCH * INC * sizeof(float);          // 16 MB

    if (ws_size >= WB_BYTES + XT_BYTES) {
        unsigned short* Wb = (unsigned short*)d_ws;
        float* XT = (float*)((char*)d_ws + WB_BYTES);
        w_prepass<<<dim3((OUTC * KDIM) / (8 * 256)), dim3(256), 0, stream>>>(W, Wb);
        xt_prepass<<<dim3(BATCH / 64, INC / 64), dim3(256), 0, stream>>>(X, XT);
        fused_gemm<true, true><<<grid, dim3(THREADS), 0, stream>>>(
            X, Wb, XT, CEN, SLP, Y);
    } else if (ws_size >= WB_BYTES) {
        unsigned short* Wb = (unsigned short*)d_ws;
        w_prepass<<<dim3((OUTC * KDIM) / (8 * 256)), dim3(256), 0, stream>>>(W, Wb);
        fused_gemm<true, false><<<grid, dim3(THREADS), 0, stream>>>(
            X, Wb, nullptr, CEN, SLP, Y);
    } else {
        fused_gemm<false, false><<<grid, dim3(THREADS), 0, stream>>>(
            X, (const void*)W, nullptr, CEN, SLP, Y);
    }
}

// Round 5
// 141.717 us; speedup vs baseline: 1.1291x; 1.1291x over previous
//
#include <hip/hip_runtime.h>

#define BATCH 8192
#define INC   512
#define OUTC  512
#define NB    8
#define KDIM  (INC * NB)     // 4096
#define BM 128
#define BN 128
#define BK 64
#define NKT (KDIM / BK)      // 64
#define THREADS 512

typedef __attribute__((ext_vector_type(8))) short bf16x8;
typedef __attribute__((ext_vector_type(4))) float f32x4;
typedef __attribute__((ext_vector_type(4))) int   i32x4;

// truncate-pack two fp32 into two bf16 (lo -> low 16 bits) in one v_perm_b32
static __device__ __forceinline__ unsigned int pk2(float lo, float hi) {
    return __builtin_amdgcn_perm(__builtin_bit_cast(unsigned int, hi),
                                 __builtin_bit_cast(unsigned int, lo),
                                 0x07060302u);
}

// ---- prepass 1: W fp32 -> bf16 (RNE) ----
__global__ __launch_bounds__(256)
void w_prepass(const float* __restrict__ W, unsigned short* __restrict__ Wb) {
    const int base = (blockIdx.x * 256 + threadIdx.x) * 8;
    const float4 a = *(const float4*)(W + base);
    const float4 b = *(const float4*)(W + base + 4);
    const float v[8] = {a.x, a.y, a.z, a.w, b.x, b.y, b.z, b.w};
    unsigned int r[8];
#pragma unroll
    for (int i = 0; i < 8; ++i) {
        unsigned int t = __builtin_bit_cast(unsigned int, v[i]);
        t += 0x7FFFu + ((t >> 16) & 1u);
        r[i] = t >> 16;
    }
    *(i32x4*)(Wb + base) = (i32x4){(int)(r[0] | (r[1] << 16)), (int)(r[2] | (r[3] << 16)),
                                   (int)(r[4] | (r[5] << 16)), (int)(r[6] | (r[7] << 16))};
}

// ---- prepass 2: X (BATCH,INC) -> XT (INC,BATCH) fp32 ----
__global__ __launch_bounds__(256)
void xt_prepass(const float* __restrict__ X, float* __restrict__ XT) {
    __shared__ float t[64][65];
    const int bx = blockIdx.x * 64;
    const int iy = blockIdx.y * 64;
    const int lx = threadIdx.x & 63;
    const int ly = threadIdx.x >> 6;
#pragma unroll
    for (int r = 0; r < 16; ++r) {
        const int row = ly * 16 + r;
        t[row][lx] = X[(size_t)(bx + row) * INC + iy + lx];
    }
    __syncthreads();
#pragma unroll
    for (int r = 0; r < 16; ++r) {
        const int row = ly * 16 + r;
        XT[(size_t)(iy + row) * BATCH + bx + lx] = t[lx][row];
    }
}

// B LDS layout (XOR-swizzled, verified r3): element (row 0..127, kblk 0..7) at
// short offset row*64 + (kblk ^ (row&7))*8.
template <bool DMA, bool XTP>
__global__ __launch_bounds__(THREADS, 2)
void fused_gemm(const float* __restrict__ X,    // (BATCH, INC)
                const void*  __restrict__ Wsrc, // bf16 ws or fp32 W
                const float* __restrict__ XT,   // (INC, BATCH) or null
                const float* __restrict__ CEN,
                const float* __restrict__ SLP,
                float* __restrict__ Y)          // (BATCH, OUTC)
{
    __shared__ short Bs[2][BN * BK];  // 2 x 16 KB

    const int tid  = threadIdx.x;
    const int lane = tid & 63;
    const int wave = tid >> 6;     // 0..7
    const int wm   = wave & 3;     // 4 m-waves, 32 rows each
    const int wn   = wave >> 2;    // 2 n-waves, 64 cols each
    const int l15  = lane & 15;
    const int h    = lane >> 4;    // 0..3
    const int low3 = lane & 7;

    const int b0 = blockIdx.x * BM;
    const int j0 = blockIdx.y * BN;

    // sigmoid: s_m(x) = 1/(1 + exp2(pc*x + q0) * R^m)
    const float L2E = 1.4426950408889634f;
    const float g2  = 2.0f * SLP[0] * L2E;
    const float pc  = -g2;
    const float q0  = g2 * CEN[0];
    const float R   = __builtin_amdgcn_exp2f(g2 * (CEN[1] - CEN[0]));

    // B fragment read bases
    const int brow = wn * 64 + l15;                       // row & 7 == low3
    const short* const brp0 = &Bs[0][brow * 64 + ((0 + h) ^ low3) * 8];
    const short* const brp1 = &Bs[0][brow * 64 + ((4 + h) ^ low3) * 8];

    // DMA global-side swizzle
    const int dma_r  = lane >> 3;
    const int dma_kb = (lane & 7) ^ dma_r;

    const int mbase = b0 + wm * 32 + l15;   // + mf*16

    f32x4 acc[2][4];
#pragma unroll
    for (int i = 0; i < 2; ++i)
#pragma unroll
        for (int j = 0; j < 4; ++j)
            acc[i][j] = (f32x4){0.f, 0.f, 0.f, 0.f};

    float xv[4], xn[4];   // [ks*2 + mf]

#define LOADX(kt, dst)                                                         \
    {                                                                          \
        _Pragma("unroll")                                                      \
        for (int ks = 0; ks < 2; ++ks) {                                       \
            const int ii = (kt) * 8 + ks * 4 + h;                              \
            _Pragma("unroll")                                                  \
            for (int mf = 0; mf < 2; ++mf) {                                   \
                const int bb = mbase + mf * 16;                                \
                (dst)[ks * 2 + mf] = XTP ? XT[(size_t)ii * BATCH + bb]         \
                                         : X[(size_t)bb * INC + ii];           \
            }                                                                  \
        }                                                                      \
    }

#define STAGEB(kt, buf)                                                        \
    {                                                                          \
        const int kg = (kt) * BK;                                              \
        if constexpr (DMA) {                                                   \
            const unsigned short* Wb = (const unsigned short*)Wsrc;            \
            _Pragma("unroll")                                                  \
            for (int q = 0; q < 2; ++q) {                                      \
                const int cc = wave * 2 + q;  /* 1 KB chunk, wave-uniform */   \
                const unsigned short* gp = Wb                                  \
                    + (size_t)(j0 + cc * 8 + dma_r) * KDIM + kg + dma_kb * 8;  \
                __builtin_amdgcn_global_load_lds(                              \
                    (const __attribute__((address_space(1))) void*)gp,         \
                    (__attribute__((address_space(3))) void*)(&Bs[buf][cc * 512]), \
                    16, 0, 0);                                                 \
            }                                                                  \
        } else {                                                               \
            const float* Wf = (const float*)Wsrc;                              \
            const int row = tid >> 2;      /* 0..127 */                        \
            const int q4  = tid & 3;       /* kblk pair */                     \
            const float* wp = Wf + (size_t)(j0 + row) * KDIM + kg + q4 * 16;   \
            _Pragma("unroll")                                                  \
            for (int p = 0; p < 2; ++p) {                                      \
                const int kb = q4 * 2 + p;                                     \
                const float4 c0 = ((const float4*)wp)[2 * p];                  \
                const float4 c1 = ((const float4*)wp)[2 * p + 1];              \
                *(i32x4*)(&Bs[buf][row * 64 + ((kb ^ (row & 7)) * 8)]) =       \
                    (i32x4){(int)pk2(c0.x, c0.y), (int)pk2(c0.z, c0.w),        \
                            (int)pk2(c1.x, c1.y), (int)pk2(c1.z, c1.w)};       \
            }                                                                  \
        }                                                                      \
    }

    // prologue
    LOADX(0, xv);
    STAGEB(0, 0);

    for (int kt = 0; kt < NKT; ++kt) {
        const int cur = kt & 1;

        __syncthreads();   // buf[cur] staged (compiler drains vmcnt/lgkm)

        if (kt + 1 < NKT) STAGEB(kt + 1, 1 - cur);
        const int ktn = (kt + 1 < NKT) ? (kt + 1) : (NKT - 1);
        LOADX(ktn, xn);

#pragma unroll
        for (int ks = 0; ks < 2; ++ks) {
            const short* brp = (ks ? brp1 : brp0) + cur * (BN * BK);
            bf16x8 bfr[4];
#pragma unroll
            for (int nf = 0; nf < 4; ++nf)
                bfr[nf] = *(const bf16x8*)(brp + nf * 1024);

            // A fragments in registers: lane's 8 k-elems = 8 basis of one (b,i)
            bf16x8 af[2];
#pragma unroll
            for (int mf = 0; mf < 2; ++mf) {
                float e = __builtin_amdgcn_exp2f(fmaf(pc, xv[ks * 2 + mf], q0));
                float s[NB];
#pragma unroll
                for (int m = 0; m < NB; ++m) {
                    s[m] = __builtin_amdgcn_rcpf(1.0f + e);
                    e *= R;
                }
                af[mf] = __builtin_bit_cast(bf16x8,
                    (i32x4){(int)pk2(s[0], s[1]), (int)pk2(s[2], s[3]),
                            (int)pk2(s[4], s[5]), (int)pk2(s[6], s[7])});
            }

#pragma unroll
            for (int mf = 0; mf < 2; ++mf)
#pragma unroll
                for (int nf = 0; nf < 4; ++nf)
                    acc[mf][nf] = __builtin_amdgcn_mfma_f32_16x16x32_bf16(
                        af[mf], bfr[nf], acc[mf][nf], 0, 0, 0);
        }

#pragma unroll
        for (int q = 0; q < 4; ++q) xv[q] = xn[q];
    }

    // epilogue: C/D layout col=lane&15, row=(lane>>4)*4+reg ; plain stores
    const int rowb = b0 + wm * 32 + h * 4;
    const int colb = j0 + wn * 64 + l15;
#pragma unroll
    for (int mf = 0; mf < 2; ++mf)
#pragma unroll
        for (int nf = 0; nf < 4; ++nf)
#pragma unroll
            for (int r = 0; r < 4; ++r)
                Y[(size_t)(rowb + mf * 16 + r) * OUTC + (colb + nf * 16)] =
                    acc[mf][nf][r];
#undef LOADX
#undef STAGEB
}

extern "C" void kernel_launch(void* const* d_in, const int* in_sizes, int n_in,
                              void* d_out, int out_size, void* d_ws, size_t ws_size,
                              hipStream_t stream) {
    const float* X   = (const float*)d_in[0];
    const float* W   = (const float*)d_in[1];
    const float* CEN = (const float*)d_in[2];
    const float* SLP = (const float*)d_in[3];
    float* Y = (float*)d_out;

    static_assert(BATCH % BM == 0 && OUTC % BN == 0 && KDIM % BK == 0, "tiling");
    dim3 grid(BATCH / BM, OUTC / BN);   // 64 x 4 = 256 blocks, 8 waves each

    const size_t WB_BYTES = (size_t)OUTC * KDIM * sizeof(unsigned short); // 4 MB
    const size_t XT_BYTES = (size_t)BATCH * INC * sizeof(float);          // 16 MB

    if (ws_size >= WB_BYTES + XT_BYTES) {
        unsigned short* Wb = (unsigned short*)d_ws;
        float* XT = (float*)((char*)d_ws + WB_BYTES);
        w_prepass<<<dim3((OUTC * KDIM) / (8 * 256)), dim3(256), 0, stream>>>(W, Wb);
        xt_prepass<<<dim3(BATCH / 64, INC / 64), dim3(256), 0, stream>>>(X, XT);
        fused_gemm<true, true><<<grid, dim3(THREADS), 0, stream>>>(
            X, Wb, XT, CEN, SLP, Y);
    } else if (ws_size >= WB_BYTES) {
        unsigned short* Wb = (unsigned short*)d_ws;
        w_prepass<<<dim3((OUTC * KDIM) / (8 * 256)), dim3(256), 0, stream>>>(W, Wb);
        fused_gemm<true, false><<<grid, dim3(THREADS), 0, stream>>>(
            X, Wb, nullptr, CEN, SLP, Y);
    } else {
        fused_gemm<false, false><<<grid, dim3(THREADS), 0, stream>>>(
            X, (const void*)W, nullptr, CEN, SLP, Y);
    }
}